// Round 3
// baseline (255.770 us; speedup 1.0000x reference)
//
#include <hip/hip_runtime.h>

#define HID 1024
#define SEQ 2048
#define NB 4
#define BS 8192  // NB*SEQ

typedef __attribute__((ext_vector_type(8))) short short8;
typedef __attribute__((ext_vector_type(8))) unsigned short ushort8;
typedef __attribute__((ext_vector_type(4))) float f32x4;

__device__ __forceinline__ float bf2f(unsigned short u) {
  unsigned int x = ((unsigned int)u) << 16;
  return __builtin_bit_cast(float, x);
}
__device__ __forceinline__ unsigned short f2bf(float f) {
  unsigned int x = __builtin_bit_cast(unsigned int, f);
  x = x + 0x7fffu + ((x >> 16) & 1u);
  return (unsigned short)(x >> 16);
}

#define GLOAD16(g, l)                                                          \
  __builtin_amdgcn_global_load_lds(                                            \
      (const __attribute__((address_space(1))) unsigned int*)(g),              \
      (__attribute__((address_space(3))) unsigned int*)(l), 16, 0, 0)

template <int N>
__device__ __forceinline__ void vmwait() {
  asm volatile("s_waitcnt vmcnt(%0)" ::"i"(N) : "memory");
}

// ---------------- fp32 -> bf16 cast, 8 elems/thread ----------------
__global__ void cast_f32_to_bf16(const float* __restrict__ in,
                                 unsigned short* __restrict__ out, int n) {
  int i = (blockIdx.x * 256 + threadIdx.x) * 8;
  if (i >= n) return;
  f32x4 a = *(const f32x4*)(in + i);
  f32x4 b = *(const f32x4*)(in + i + 4);
  ushort8 o;
  o[0] = f2bf(a[0]); o[1] = f2bf(a[1]); o[2] = f2bf(a[2]); o[3] = f2bf(a[3]);
  o[4] = f2bf(b[0]); o[5] = f2bf(b[1]); o[6] = f2bf(b[2]); o[7] = f2bf(b[3]);
  *(ushort8*)(out + i) = o;
}

// ------------- 1024x1024 fp32 -> bf16 transposed cast -------------
__global__ __launch_bounds__(256) void transpose_cast(
    const float* __restrict__ in, unsigned short* __restrict__ out) {
  __shared__ float t[32][33];
  const int bx = blockIdx.x * 32, by = blockIdx.y * 32;
  const int tx = threadIdx.x & 31, ty = threadIdx.x >> 5;  // 32 x 8
#pragma unroll
  for (int i = 0; i < 4; ++i)
    t[ty + i * 8][tx] = in[(by + ty + i * 8) * 1024 + bx + tx];
  __syncthreads();
#pragma unroll
  for (int i = 0; i < 4; ++i)
    out[(bx + ty + i * 8) * 1024 + by + tx] = f2bf(t[tx][ty + i * 8]);
}

// ------------- b'[h] = bo[h] + sum_k Wo[h,k] * bv[k] -------------
__global__ __launch_bounds__(256) void bias_fuse(const float* __restrict__ Wo,
                                                 const float* __restrict__ bv,
                                                 const float* __restrict__ bo,
                                                 float* __restrict__ bp) {
  const int h = blockIdx.x * 256 + threadIdx.x;
  float s = bo[h];
  for (int k = 0; k < 1024; ++k) s += Wo[h * 1024 + k] * bv[k];
  bp[h] = s;
}

// ======================= 256 x BN 8-phase NT GEMM ==========================
// C[m,n] = alpha * sum_k A[m,k]*B[n,k] (+bias). BM=256, BK=64, 512 thr.
// BIAS_MODE: 0 none, 1 bias[col], 2 bias[row], 3 col<1024?bias:bias2.
template <int BN, int OUT_F32, int BIAS_MODE>
__global__ __launch_bounds__(512, 2) void gemm8p(
    const unsigned short* __restrict__ A, const unsigned short* __restrict__ B,
    void* __restrict__ Cv, const float* __restrict__ bias,
    const float* __restrict__ bias2, int K, int lda, int ldb, int ldc,
    long long bsA, long long bsB, long long bsC, float alpha) {
  static_assert(BN == 256 || BN == 128, "BN");
  constexpr int WMW = (BN == 256) ? 2 : 4;  // waves along M
  constexpr int WNW = 8 / WMW;              // waves along N
  constexpr int MF = 8 / WMW;               // M frags per quadrant-phase
  constexpr int NF = 2;                     // N frags per quadrant-phase
  constexpr int NBH = BN / 2;               // B half-tile rows
  constexpr int GB = (BN == 256) ? 2 : 1;   // gloads per B half-tile stage
  constexpr int BSLOT = NBH * 64;           // ushorts per B half-slot
  // Counted vmcnt keeps (derived from issue->consume distances; see notes):
  constexpr int WK0 = (BN == 256) ? 6 : 5;  // p0/p4-end keep
  constexpr int WK3 = (BN == 256) ? 8 : 6;  // p3/p7-end keep
  constexpr int WPR = (BN == 256) ? 4 : 3;  // prologue keep (tile1-h0 in flight)

  __shared__ unsigned short ldsA[4 * 8192];   // [buf*2+half][128x64]
  __shared__ unsigned short ldsB[4 * BSLOT];  // [buf*2+half][NBH x 64]

  const int tid = threadIdx.x;
  const int lane = tid & 63, wid = tid >> 6;
  const int fr = lane & 15, fq = lane >> 4;
  const int wm = wid / WNW, wn = wid % WNW;

  // T1: XCD-aware block swizzle over flattened (y,x). All launches have
  // gridDim.x*gridDim.y % 8 == 0.
  const int nx = gridDim.x;
  const int nwg = nx * gridDim.y;
  int f = blockIdx.y * nx + blockIdx.x;
  f = (f & 7) * (nwg >> 3) + (f >> 3);
  const int bx = f % nx, by = f / nx;
  const int bz = blockIdx.z;

  const unsigned short* Ag = A + bz * bsA + (long long)by * 256 * lda;
  const unsigned short* Bg = B + bz * bsB + (long long)bx * BN * ldb;
  const int NT = K >> 6;

  // Staging: LDS write is linear (base + lane*16B); the LDS XOR-swizzle
  // (bits[6:4] ^= bits[10:8]) is applied to the GLOBAL source instead
  // (involution; both sides must match - rule 21).
  const int La0 = wid * 1024 + lane * 16;
  const int La1 = 8192 + La0;
  const int Pa0 = La0 ^ ((La0 >> 4) & 0x70);
  const int Pa1 = La1 ^ ((La1 >> 4) & 0x70);
  const int aR0 = Pa0 >> 7, aC0 = (Pa0 & 127) >> 1;
  const int aR1 = Pa1 >> 7, aC1 = (Pa1 & 127) >> 1;

  auto stageA = [&](int tile, int h) {
    if (tile >= NT) return;
    unsigned short* d = &ldsA[(((tile & 1) << 1) | h) * 8192 + wid * 512];
    GLOAD16(Ag + (long long)(h * 128 + aR0) * lda + tile * 64 + aC0, d);
    GLOAD16(Ag + (long long)(h * 128 + aR1) * lda + tile * 64 + aC1, d + 4096);
  };
  auto stageB = [&](int tile, int h) {
    if (tile >= NT) return;
    unsigned short* d = &ldsB[(((tile & 1) << 1) | h) * BSLOT + wid * 512];
    GLOAD16(Bg + (long long)(h * NBH + aR0) * ldb + tile * 64 + aC0, d);
    if (GB == 2)
      GLOAD16(Bg + (long long)(h * NBH + aR1) * ldb + tile * 64 + aC1, d + 4096);
  };

  // Fragment ds_read offsets (swizzled), ushort units.
  int offA[MF][2], offB[NF][2];
#pragma unroll
  for (int i = 0; i < MF; ++i)
#pragma unroll
    for (int s = 0; s < 2; ++s) {
      int b = (wm * (128 / WMW) + i * 16 + fr) * 128 + s * 64 + fq * 16;
      offA[i][s] = (b ^ ((b >> 4) & 0x70)) >> 1;
    }
#pragma unroll
  for (int n = 0; n < NF; ++n)
#pragma unroll
    for (int s = 0; s < 2; ++s) {
      int b = (wn * 32 + n * 16 + fr) * 128 + s * 64 + fq * 16;
      offB[n][s] = (b ^ ((b >> 4) & 0x70)) >> 1;
    }

  f32x4 acc[2][2][MF][NF] = {};

  // Prologue: tile0 fully + tile1-h0; leave tile1-h0 loads in flight.
  stageA(0, 0); stageB(0, 0); stageA(0, 1); stageB(0, 1);
  stageA(1, 0); stageB(1, 0);
  vmwait<WPR>();
  __builtin_amdgcn_s_barrier();

  for (int kt = 0; kt < NT; kt += 2) {
    const bool tail = (kt + 2 >= NT);
#pragma unroll
    for (int t2 = 0; t2 < 2; ++t2) {
      const int buf = (kt + t2) & 1;
#pragma unroll
      for (int ph = 0; ph < 4; ++ph) {
        const int mh = ph >> 1, nh = ph & 1;
        const int p = t2 * 4 + ph;
        short8 av[MF][2], bw[NF][2];
        const unsigned short* pa = &ldsA[((buf << 1) | mh) * 8192];
        const unsigned short* pb = &ldsB[((buf << 1) | nh) * BSLOT];
#pragma unroll
        for (int i = 0; i < MF; ++i)
#pragma unroll
          for (int s = 0; s < 2; ++s)
            av[i][s] = *(const short8*)(pa + offA[i][s]);
#pragma unroll
        for (int n = 0; n < NF; ++n)
#pragma unroll
          for (int s = 0; s < 2; ++s)
            bw[n][s] = *(const short8*)(pb + offB[n][s]);
        // Stage schedule (max depth for 2 LDS buffers): each slot's overwrite
        // issues one phase after the last read of its previous occupant.
        if (p == 0) stageA(kt + 1, 1);
        else if (p == 1) stageB(kt + 1, 1);
        else if (p == 2) stageA(kt + 2, 0);
        else if (p == 3) stageB(kt + 2, 0);
        else if (p == 4) stageA(kt + 2, 1);
        else if (p == 5) stageB(kt + 2, 1);
        else if (p == 6) stageA(kt + 3, 0);
        else stageB(kt + 3, 0);
        __builtin_amdgcn_s_barrier();
        __builtin_amdgcn_s_setprio(1);
#pragma unroll
        for (int i = 0; i < MF; ++i)
#pragma unroll
          for (int n = 0; n < NF; ++n)
#pragma unroll
            for (int s = 0; s < 2; ++s)
              acc[mh][nh][i][n] = __builtin_amdgcn_mfma_f32_16x16x32_bf16(
                  av[i][s], bw[n][s], acc[mh][nh][i][n], 0, 0, 0);
        __builtin_amdgcn_s_setprio(0);
        // Counted waits, placed before the phase-end barrier that publishes
        // them. Deps land 4-6 phases after issue. Tail: stages were skipped,
        // steady-state younger-load counts invalid -> full drain (FIFO safety).
        if (p == 0) vmwait<WK0>();
        else if (p == 3) { if (tail) vmwait<0>(); else vmwait<WK3>(); }
        else if (p == 4) { if (tail) vmwait<0>(); else vmwait<WK0>(); }
        else if (p == 7) vmwait<WK3>();
        __builtin_amdgcn_s_barrier();
      }
    }
  }

  // Epilogue. C/D frag layout: col = 16*frag + fr, row = fq*4 + j.
  const long long cb0 = (long long)bz * bsC;
#pragma unroll
  for (int mh = 0; mh < 2; ++mh)
#pragma unroll
    for (int nh = 0; nh < 2; ++nh)
#pragma unroll
      for (int i = 0; i < MF; ++i)
#pragma unroll
        for (int n = 0; n < NF; ++n) {
          const int col = bx * BN + nh * NBH + wn * 32 + n * 16 + fr;
          float cbias = 0.f;
          if (BIAS_MODE == 1) cbias = bias[col];
          if (BIAS_MODE == 3)
            cbias = (col < 1024) ? bias[col] : bias2[col - 1024];
#pragma unroll
          for (int j = 0; j < 4; ++j) {
            const int row =
                by * 256 + mh * 128 + wm * (128 / WMW) + i * 16 + fq * 4 + j;
            float v = acc[mh][nh][i][n][j] * alpha + cbias;
            if (BIAS_MODE == 2) v += bias[row];
            const long long idx = cb0 + (long long)row * ldc + col;
            if (OUT_F32)
              ((float*)Cv)[idx] = v;
            else
              ((unsigned short*)Cv)[idx] = f2bf(v);
          }
        }
}

// ---------------- in-place row softmax over 2048 bf16 ----------------
__global__ __launch_bounds__(256) void softmax_inplace(
    unsigned short* __restrict__ P) {
  __shared__ float red[8];
  unsigned short* p = P + (long long)blockIdx.x * 2048;
  const int tid = threadIdx.x;
  const int lane = tid & 63, w = tid >> 6;
  ushort8 v = *(const ushort8*)(p + tid * 8);
  float f[8];
#pragma unroll
  for (int i = 0; i < 8; ++i) f[i] = bf2f(v[i]);
  float mx = f[0];
#pragma unroll
  for (int i = 1; i < 8; ++i) mx = fmaxf(mx, f[i]);
#pragma unroll
  for (int off = 32; off >= 1; off >>= 1)
    mx = fmaxf(mx, __shfl_xor(mx, off, 64));
  if (lane == 0) red[w] = mx;
  __syncthreads();
  mx = fmaxf(fmaxf(red[0], red[1]), fmaxf(red[2], red[3]));
  float s = 0.f;
#pragma unroll
  for (int i = 0; i < 8; ++i) {
    f[i] = __expf(f[i] - mx);
    s += f[i];
  }
#pragma unroll
  for (int off = 32; off >= 1; off >>= 1) s += __shfl_xor(s, off, 64);
  if (lane == 0) red[4 + w] = s;
  __syncthreads();
  s = (red[4] + red[5]) + (red[6] + red[7]);
  const float inv = 1.0f / s;
  ushort8 o;
#pragma unroll
  for (int i = 0; i < 8; ++i) o[i] = f2bf(f[i] * inv);
  *(ushort8*)(p + tid * 8) = o;
}

extern "C" void kernel_launch(void* const* d_in, const int* in_sizes, int n_in,
                              void* d_out, int out_size, void* d_ws,
                              size_t ws_size, hipStream_t stream) {
  (void)in_sizes; (void)n_in; (void)out_size; (void)ws_size;
  const float* x = (const float*)d_in[0];
  const float* Wq = (const float*)d_in[1];
  const float* bq = (const float*)d_in[2];
  const float* Wk = (const float*)d_in[3];
  const float* bk = (const float*)d_in[4];
  const float* Wv = (const float*)d_in[5];
  const float* bv = (const float*)d_in[6];
  const float* Wo = (const float*)d_in[7];
  const float* bo = (const float*)d_in[8];
  float* out = (float*)d_out;

  char* ws = (char*)d_ws;
  unsigned short* xbf  = (unsigned short*)(ws + 0);         // 16 MiB
  unsigned short* wqk  = (unsigned short*)(ws + 16777216);  // 4 MiB [2048][1024]
  unsigned short* wobf = (unsigned short*)(ws + 20971520);  // 2 MiB
  unsigned short* wvT  = (unsigned short*)(ws + 23068672);  // 2 MiB (Wv^T)
  unsigned short* wov  = (unsigned short*)(ws + 25165824);  // 2 MiB (Wo.Wv)
  float*          bpr  = (float*)        (ws + 27262976);   // 4 KiB (Wo.bv+bo)
  unsigned short* VWoT = (unsigned short*)(ws + 33554432);  // 16 MiB [1024][8192]
  unsigned short* QKb  = (unsigned short*)(ws + 50331648);  // 32 MiB [8192][2048]
  unsigned short* P    = (unsigned short*)(ws + 83886080);  // 32 MiB [4][2048][2048]
  // total 117,440,512 bytes

  // casts & small precomputes
  cast_f32_to_bf16<<<4096, 256, 0, stream>>>(x, xbf, BS * HID);
  cast_f32_to_bf16<<<512, 256, 0, stream>>>(Wq, wqk, HID * HID);
  cast_f32_to_bf16<<<512, 256, 0, stream>>>(Wk, wqk + HID * HID, HID * HID);
  cast_f32_to_bf16<<<512, 256, 0, stream>>>(Wo, wobf, HID * HID);
  transpose_cast<<<dim3(32, 32), 256, 0, stream>>>(Wv, wvT);
  bias_fuse<<<4, 256, 0, stream>>>(Wo, bv, bo, bpr);

  // WoWv[h,k] = sum_j Wo[h,j] Wv[j,k] = NT(Wo, Wv^T) : [1024,1024]
  gemm8p<128, 0, 0><<<dim3(8, 4, 1), 512, 0, stream>>>(
      wobf, wvT, wov, nullptr, nullptr, HID, HID, HID, HID, 0, 0, 0, 1.0f);
  // VWoT[h,s] = sum_k WoWv[h,k] x[s,k] = NT(WoWv, x) : [1024,8192]
  gemm8p<128, 0, 0><<<dim3(64, 4, 1), 512, 0, stream>>>(
      wov, xbf, VWoT, nullptr, nullptr, HID, HID, HID, BS, 0, 0, 0, 1.0f);
  // [Q|K] = x @ [Wq;Wk]^T + [bq;bk] : [8192,2048]
  gemm8p<256, 0, 3><<<dim3(8, 32, 1), 512, 0, stream>>>(
      xbf, wqk, QKb, bq, bk, HID, HID, HID, 2048, 0, 0, 0, 1.0f);
  // P = Q @ K^T / 32 per batch : [4][2048][2048]
  gemm8p<256, 0, 0><<<dim3(8, 8, NB), 512, 0, stream>>>(
      QKb, QKb + 1024, P, nullptr, nullptr, HID, 2048, 2048, SEQ,
      (long long)SEQ * 2048, (long long)SEQ * 2048, (long long)SEQ * SEQ,
      0.03125f);
  // softmax rows in place
  softmax_inplace<<<BS, 256, 0, stream>>>(P);
  // out = attn @ VWoT^T + b' : [8192,1024] fp32 (k-window shift via bsB)
  gemm8p<128, 1, 1><<<dim3(8, 8, NB), 512, 0, stream>>>(
      P, VWoT, out, bpr, nullptr, SEQ, SEQ, BS, HID, (long long)SEQ * SEQ,
      (long long)SEQ, (long long)SEQ * HID, 1.0f);
}

// Round 4
// 246.438 us; speedup vs baseline: 1.0379x; 1.0379x over previous
//
#include <hip/hip_runtime.h>

#define HID 1024
#define SEQ 2048
#define NB 4
#define BS 8192  // NB*SEQ

typedef __attribute__((ext_vector_type(8))) short short8;
typedef __attribute__((ext_vector_type(8))) unsigned short ushort8;
typedef __attribute__((ext_vector_type(4))) float f32x4;

__device__ __forceinline__ float bf2f(unsigned short u) {
  unsigned int x = ((unsigned int)u) << 16;
  return __builtin_bit_cast(float, x);
}
__device__ __forceinline__ unsigned short f2bf(float f) {
  unsigned int x = __builtin_bit_cast(unsigned int, f);
  x = x + 0x7fffu + ((x >> 16) & 1u);
  return (unsigned short)(x >> 16);
}

#define GLOAD16(g, l)                                                          \
  __builtin_amdgcn_global_load_lds(                                            \
      (const __attribute__((address_space(1))) unsigned int*)(g),              \
      (__attribute__((address_space(3))) unsigned int*)(l), 16, 0, 0)

template <int N>
__device__ __forceinline__ void vmwait() {
  asm volatile("s_waitcnt vmcnt(%0)" ::"i"(N) : "memory");
}

// ---------------- fp32 -> bf16 cast, 8 elems/thread ----------------
__global__ void cast_f32_to_bf16(const float* __restrict__ in,
                                 unsigned short* __restrict__ out, int n) {
  int i = (blockIdx.x * 256 + threadIdx.x) * 8;
  if (i >= n) return;
  f32x4 a = *(const f32x4*)(in + i);
  f32x4 b = *(const f32x4*)(in + i + 4);
  ushort8 o;
  o[0] = f2bf(a[0]); o[1] = f2bf(a[1]); o[2] = f2bf(a[2]); o[3] = f2bf(a[3]);
  o[4] = f2bf(b[0]); o[5] = f2bf(b[1]); o[6] = f2bf(b[2]); o[7] = f2bf(b[3]);
  *(ushort8*)(out + i) = o;
}

// ------------- 1024x1024 fp32 -> bf16 transposed cast -------------
__global__ __launch_bounds__(256) void transpose_cast(
    const float* __restrict__ in, unsigned short* __restrict__ out) {
  __shared__ float t[32][33];
  const int bx = blockIdx.x * 32, by = blockIdx.y * 32;
  const int tx = threadIdx.x & 31, ty = threadIdx.x >> 5;  // 32 x 8
#pragma unroll
  for (int i = 0; i < 4; ++i)
    t[ty + i * 8][tx] = in[(by + ty + i * 8) * 1024 + bx + tx];
  __syncthreads();
#pragma unroll
  for (int i = 0; i < 4; ++i)
    out[(bx + ty + i * 8) * 1024 + by + tx] = f2bf(t[tx][ty + i * 8]);
}

// ------------- b'[h] = bo[h] + sum_k Wo[h,k] * bv[k] -------------
__global__ __launch_bounds__(256) void bias_fuse(const float* __restrict__ Wo,
                                                 const float* __restrict__ bv,
                                                 const float* __restrict__ bo,
                                                 float* __restrict__ bp) {
  const int h = blockIdx.x * 256 + threadIdx.x;
  float s = bo[h];
  for (int k = 0; k < 1024; ++k) s += Wo[h * 1024 + k] * bv[k];
  bp[h] = s;
}

// ======================= 256 x BN 8-phase NT GEMM ==========================
// C[m,n] = alpha * sum_k A[m,k]*B[n,k] (+bias). BM=256, BK=64, 512 thr.
// BIAS_MODE: 0 none, 1 bias[col], 3 col<1024?bias:bias2.
// SWZ: 0 row-chunk XCD swizzle, 1 z-paired (grid must be (8,8,z)),
//      2 col-chunk XCD swizzle.
// EPI: 0 plain, 1 exp(e)+rowsum->Srow atomics (QK^T), 2 scale by 1/Srow.
template <int BN, int OUT_F32, int BIAS_MODE, int SWZ, int EPI>
__global__ __launch_bounds__(512, 2) void gemm8p(
    const unsigned short* __restrict__ A, const unsigned short* __restrict__ B,
    void* __restrict__ Cv, const float* __restrict__ bias,
    const float* __restrict__ bias2, float* __restrict__ Srow, int K, int lda,
    int ldb, int ldc, long long bsA, long long bsB, long long bsC,
    float alpha) {
  static_assert(BN == 256 || BN == 128, "BN");
  constexpr int WMW = (BN == 256) ? 2 : 4;  // waves along M
  constexpr int WNW = 8 / WMW;              // waves along N
  constexpr int MF = 8 / WMW;               // M frags per quadrant-phase
  constexpr int NF = 2;                     // N frags per quadrant-phase
  constexpr int NBH = BN / 2;               // B half-tile rows
  constexpr int GB = (BN == 256) ? 2 : 1;   // gloads per B half-tile stage
  constexpr int BSLOT = NBH * 64;           // ushorts per B half-slot
  constexpr int WK0 = (BN == 256) ? 6 : 5;  // p0/p4-end keep
  constexpr int WK3 = (BN == 256) ? 8 : 6;  // p3/p7-end keep
  constexpr int WPR = (BN == 256) ? 4 : 3;  // prologue keep

  __shared__ unsigned short ldsA[4 * 8192];   // [buf*2+half][128x64]
  __shared__ unsigned short ldsB[4 * BSLOT];  // [buf*2+half][NBH x 64]

  const int tid = threadIdx.x;
  const int lane = tid & 63, wid = tid >> 6;
  const int fr = lane & 15, fq = lane >> 4;
  const int wm = wid / WNW, wn = wid % WNW;

  int bx, by, bz;
  if (SWZ == 1) {
    // z-paired: 2 XCDs own one z; each takes 4 by-rows x 8 bx. grid (8,8,z).
    const int h = (blockIdx.z * 8 + blockIdx.y) * 8 + blockIdx.x;
    const int xcd = h & 7, j = h >> 3;  // j in [0, 8*gz)
    const int zs = j / 32;              // extra z layers if gz>4 (unused here)
    bz = (xcd >> 1) + zs * 4;
    const int tile = (xcd & 1) * 32 + (j & 31);
    by = tile >> 3;
    bx = tile & 7;
  } else if (SWZ == 2) {
    const int nx = gridDim.x, nwg = nx * gridDim.y;
    int h = blockIdx.y * nx + blockIdx.x;
    int f = (h & 7) * (nwg >> 3) + (h >> 3);
    by = f % gridDim.y;
    bx = f / gridDim.y;
    bz = blockIdx.z;
  } else {
    const int nx = gridDim.x, nwg = nx * gridDim.y;
    int h = blockIdx.y * nx + blockIdx.x;
    int f = (h & 7) * (nwg >> 3) + (h >> 3);
    bx = f % nx;
    by = f / nx;
    bz = blockIdx.z;
  }

  const unsigned short* Ag = A + bz * bsA + (long long)by * 256 * lda;
  const unsigned short* Bg = B + bz * bsB + (long long)bx * BN * ldb;
  const int NT = K >> 6;

  // Staging: LDS write is linear (base + lane*16B); the LDS XOR-swizzle
  // (bits[6:4] ^= bits[10:8]) is applied to the GLOBAL source instead
  // (involution; both sides must match - rule 21).
  const int La0 = wid * 1024 + lane * 16;
  const int La1 = 8192 + La0;
  const int Pa0 = La0 ^ ((La0 >> 4) & 0x70);
  const int Pa1 = La1 ^ ((La1 >> 4) & 0x70);
  const int aR0 = Pa0 >> 7, aC0 = (Pa0 & 127) >> 1;
  const int aR1 = Pa1 >> 7, aC1 = (Pa1 & 127) >> 1;

  auto stageA = [&](int tile, int h) {
    if (tile >= NT) return;
    unsigned short* d = &ldsA[(((tile & 1) << 1) | h) * 8192 + wid * 512];
    GLOAD16(Ag + (long long)(h * 128 + aR0) * lda + tile * 64 + aC0, d);
    GLOAD16(Ag + (long long)(h * 128 + aR1) * lda + tile * 64 + aC1, d + 4096);
  };
  auto stageB = [&](int tile, int h) {
    if (tile >= NT) return;
    unsigned short* d = &ldsB[(((tile & 1) << 1) | h) * BSLOT + wid * 512];
    GLOAD16(Bg + (long long)(h * NBH + aR0) * ldb + tile * 64 + aC0, d);
    if (GB == 2)
      GLOAD16(Bg + (long long)(h * NBH + aR1) * ldb + tile * 64 + aC1, d + 4096);
  };

  // Fragment ds_read offsets (swizzled), ushort units.
  int offA[MF][2], offB[NF][2];
#pragma unroll
  for (int i = 0; i < MF; ++i)
#pragma unroll
    for (int s = 0; s < 2; ++s) {
      int b = (wm * (128 / WMW) + i * 16 + fr) * 128 + s * 64 + fq * 16;
      offA[i][s] = (b ^ ((b >> 4) & 0x70)) >> 1;
    }
#pragma unroll
  for (int n = 0; n < NF; ++n)
#pragma unroll
    for (int s = 0; s < 2; ++s) {
      int b = (wn * 32 + n * 16 + fr) * 128 + s * 64 + fq * 16;
      offB[n][s] = (b ^ ((b >> 4) & 0x70)) >> 1;
    }

  f32x4 acc[2][2][MF][NF] = {};

  // Prologue: tile0 fully + tile1-h0; leave tile1-h0 loads in flight.
  stageA(0, 0); stageB(0, 0); stageA(0, 1); stageB(0, 1);
  stageA(1, 0); stageB(1, 0);
  vmwait<WPR>();
  __builtin_amdgcn_s_barrier();

  for (int kt = 0; kt < NT; kt += 2) {
    const bool tail = (kt + 2 >= NT);
#pragma unroll
    for (int t2 = 0; t2 < 2; ++t2) {
      const int buf = (kt + t2) & 1;
#pragma unroll
      for (int ph = 0; ph < 4; ++ph) {
        const int mh = ph >> 1, nh = ph & 1;
        const int p = t2 * 4 + ph;
        short8 av[MF][2], bw[NF][2];
        const unsigned short* pa = &ldsA[((buf << 1) | mh) * 8192];
        const unsigned short* pb = &ldsB[((buf << 1) | nh) * BSLOT];
#pragma unroll
        for (int i = 0; i < MF; ++i)
#pragma unroll
          for (int s = 0; s < 2; ++s)
            av[i][s] = *(const short8*)(pa + offA[i][s]);
#pragma unroll
        for (int n = 0; n < NF; ++n)
#pragma unroll
          for (int s = 0; s < 2; ++s)
            bw[n][s] = *(const short8*)(pb + offB[n][s]);
        // Stage schedule: each slot's overwrite issues one phase after the
        // last read of its previous occupant (WAR safe via the barriers).
        if (p == 0) stageA(kt + 1, 1);
        else if (p == 1) stageB(kt + 1, 1);
        else if (p == 2) stageA(kt + 2, 0);
        else if (p == 3) stageB(kt + 2, 0);
        else if (p == 4) stageA(kt + 2, 1);
        else if (p == 5) stageB(kt + 2, 1);
        else if (p == 6) stageA(kt + 3, 0);
        else stageB(kt + 3, 0);
        __builtin_amdgcn_s_barrier();
        __builtin_amdgcn_s_setprio(1);
#pragma unroll
        for (int i = 0; i < MF; ++i)
#pragma unroll
          for (int n = 0; n < NF; ++n)
#pragma unroll
            for (int s = 0; s < 2; ++s)
              acc[mh][nh][i][n] = __builtin_amdgcn_mfma_f32_16x16x32_bf16(
                  av[i][s], bw[n][s], acc[mh][nh][i][n], 0, 0, 0);
        __builtin_amdgcn_s_setprio(0);
        if (p == 0) vmwait<WK0>();
        else if (p == 3) { if (tail) vmwait<0>(); else vmwait<WK3>(); }
        else if (p == 4) { if (tail) vmwait<0>(); else vmwait<WK0>(); }
        else if (p == 7) vmwait<WK3>();
        __builtin_amdgcn_s_barrier();
      }
    }
  }

  // Epilogue. C/D frag layout: col = 16*frag + fr, row = fq*4 + j.
  const long long cb0 = (long long)bz * bsC;
  float* sredf = (float*)ldsA;  // [256][WNW] row-sum scratch (EPI==1)
#pragma unroll
  for (int mh = 0; mh < 2; ++mh)
#pragma unroll
    for (int i = 0; i < MF; ++i)
#pragma unroll
      for (int j = 0; j < 4; ++j) {
        const int row = mh * 128 + wm * (128 / WMW) + i * 16 + fq * 4 + j;
        float inv = 1.0f;
        if (EPI == 2) inv = 1.0f / Srow[(long long)bz * SEQ + by * 256 + row];
        float rps = 0.0f;
#pragma unroll
        for (int nh = 0; nh < 2; ++nh)
#pragma unroll
          for (int n = 0; n < NF; ++n) {
            const int col = bx * BN + nh * NBH + wn * 32 + n * 16 + fr;
            float v = acc[mh][nh][i][n][j] * alpha;
            if (EPI == 1) { v = __expf(v); rps += v; }
            if (EPI == 2) v *= inv;
            if (BIAS_MODE == 1) v += bias[col];
            if (BIAS_MODE == 3) v += (col < 1024) ? bias[col] : bias2[col - 1024];
            const long long idx =
                cb0 + (long long)(by * 256 + row) * ldc + col;
            if (OUT_F32)
              ((float*)Cv)[idx] = v;
            else
              ((unsigned short*)Cv)[idx] = f2bf(v);
          }
        if (EPI == 1) {
          // reduce over the 16-lane fr group -> wave's 64-col row partial
          rps += __shfl_xor(rps, 1, 64);
          rps += __shfl_xor(rps, 2, 64);
          rps += __shfl_xor(rps, 4, 64);
          rps += __shfl_xor(rps, 8, 64);
          if (fr == 0) sredf[row * WNW + wn] = rps;
        }
      }
  if (EPI == 1) {
    __syncthreads();
    if (tid < 256) {
      float s4 = 0.0f;
#pragma unroll
      for (int w = 0; w < WNW; ++w) s4 += sredf[tid * WNW + w];
      atomicAdd(Srow + (long long)bz * SEQ + by * 256 + tid, s4);
    }
  }
}

extern "C" void kernel_launch(void* const* d_in, const int* in_sizes, int n_in,
                              void* d_out, int out_size, void* d_ws,
                              size_t ws_size, hipStream_t stream) {
  (void)in_sizes; (void)n_in; (void)out_size; (void)ws_size;
  const float* x = (const float*)d_in[0];
  const float* Wq = (const float*)d_in[1];
  const float* bq = (const float*)d_in[2];
  const float* Wk = (const float*)d_in[3];
  const float* bk = (const float*)d_in[4];
  const float* Wv = (const float*)d_in[5];
  const float* bv = (const float*)d_in[6];
  const float* Wo = (const float*)d_in[7];
  const float* bo = (const float*)d_in[8];
  float* out = (float*)d_out;

  char* ws = (char*)d_ws;
  unsigned short* xbf  = (unsigned short*)(ws + 0);         // 16 MiB
  unsigned short* wqk  = (unsigned short*)(ws + 16777216);  // 4 MiB [2048][1024]
  unsigned short* wobf = (unsigned short*)(ws + 20971520);  // 2 MiB
  unsigned short* wvT  = (unsigned short*)(ws + 23068672);  // 2 MiB (Wv^T)
  unsigned short* wov  = (unsigned short*)(ws + 25165824);  // 2 MiB (Wo.Wv)
  float*          bpr  = (float*)        (ws + 27262976);   // 4 KiB (Wo.bv+bo)
  float*          Srow = (float*)        (ws + 28311552);   // 32 KiB rowsums
  unsigned short* VWoT = (unsigned short*)(ws + 33554432);  // 16 MiB [1024][8192]
  unsigned short* QKb  = (unsigned short*)(ws + 50331648);  // 32 MiB [8192][2048]
  unsigned short* P    = (unsigned short*)(ws + 83886080);  // 32 MiB [4][2048][2048]

  // casts & small precomputes
  cast_f32_to_bf16<<<4096, 256, 0, stream>>>(x, xbf, BS * HID);
  cast_f32_to_bf16<<<512, 256, 0, stream>>>(Wq, wqk, HID * HID);
  cast_f32_to_bf16<<<512, 256, 0, stream>>>(Wk, wqk + HID * HID, HID * HID);
  cast_f32_to_bf16<<<512, 256, 0, stream>>>(Wo, wobf, HID * HID);
  transpose_cast<<<dim3(32, 32), 256, 0, stream>>>(Wv, wvT);
  bias_fuse<<<4, 256, 0, stream>>>(Wo, bv, bo, bpr);
  hipMemsetAsync(Srow, 0, NB * SEQ * sizeof(float), stream);

  // WoWv[h,k] = sum_j Wo[h,j] Wv[j,k] = NT(Wo, Wv^T) : [1024,1024]
  gemm8p<128, 0, 0, 0, 0><<<dim3(8, 4, 1), 512, 0, stream>>>(
      wobf, wvT, wov, nullptr, nullptr, nullptr, HID, HID, HID, HID, 0, 0, 0,
      1.0f);
  // VWoT[h,s] = sum_k WoWv[h,k] x[s,k] = NT(WoWv, x) : [1024,8192]
  gemm8p<128, 0, 0, 2, 0><<<dim3(64, 4, 1), 512, 0, stream>>>(
      wov, xbf, VWoT, nullptr, nullptr, nullptr, HID, HID, HID, BS, 0, 0, 0,
      1.0f);
  // [Q|K] = x @ [Wq;Wk]^T + [bq;bk] : [8192,2048]
  gemm8p<256, 0, 3, 0, 0><<<dim3(8, 32, 1), 512, 0, stream>>>(
      xbf, wqk, QKb, bq, bk, nullptr, HID, HID, HID, 2048, 0, 0, 0, 1.0f);
  // P = exp(Q @ K^T / 32) per batch + rowsums : [4][2048][2048]
  gemm8p<256, 0, 0, 1, 1><<<dim3(8, 8, NB), 512, 0, stream>>>(
      QKb, QKb + 1024, P, nullptr, nullptr, Srow, HID, 2048, 2048, SEQ,
      (long long)SEQ * 2048, (long long)SEQ * 2048, (long long)SEQ * SEQ,
      0.03125f);
  // out = (P @ VWoT^T) / Srow + b' : [8192,1024] fp32 (k-window via bsB)
  gemm8p<128, 1, 1, 1, 2><<<dim3(8, 8, NB), 512, 0, stream>>>(
      P, VWoT, out, bpr, nullptr, Srow, SEQ, SEQ, BS, HID,
      (long long)SEQ * SEQ, (long long)SEQ, (long long)SEQ * HID, 1.0f);
}

// Round 5
// 234.522 us; speedup vs baseline: 1.0906x; 1.0508x over previous
//
#include <hip/hip_runtime.h>

#define HID 1024
#define SEQ 2048
#define NB 4
#define BS 8192  // NB*SEQ

typedef __attribute__((ext_vector_type(8))) short short8;
typedef __attribute__((ext_vector_type(8))) unsigned short ushort8;
typedef __attribute__((ext_vector_type(4))) float f32x4;

__device__ __forceinline__ float bf2f(unsigned short u) {
  unsigned int x = ((unsigned int)u) << 16;
  return __builtin_bit_cast(float, x);
}
__device__ __forceinline__ unsigned short f2bf(float f) {
  unsigned int x = __builtin_bit_cast(unsigned int, f);
  x = x + 0x7fffu + ((x >> 16) & 1u);
  return (unsigned short)(x >> 16);
}

#define GLOAD16(g, l)                                                          \
  __builtin_amdgcn_global_load_lds(                                            \
      (const __attribute__((address_space(1))) unsigned int*)(g),              \
      (__attribute__((address_space(3))) unsigned int*)(l), 16, 0, 0)

// ---------------- fp32 -> bf16 cast, 8 elems/thread ----------------
__global__ void cast_f32_to_bf16(const float* __restrict__ in,
                                 unsigned short* __restrict__ out, int n) {
  int i = (blockIdx.x * 256 + threadIdx.x) * 8;
  if (i >= n) return;
  f32x4 a = *(const f32x4*)(in + i);
  f32x4 b = *(const f32x4*)(in + i + 4);
  ushort8 o;
  o[0] = f2bf(a[0]); o[1] = f2bf(a[1]); o[2] = f2bf(a[2]); o[3] = f2bf(a[3]);
  o[4] = f2bf(b[0]); o[5] = f2bf(b[1]); o[6] = f2bf(b[2]); o[7] = f2bf(b[3]);
  *(ushort8*)(out + i) = o;
}

// ------------- 1024x1024 fp32 -> bf16 transposed cast -------------
__global__ __launch_bounds__(256) void transpose_cast(
    const float* __restrict__ in, unsigned short* __restrict__ out) {
  __shared__ float t[32][33];
  const int bx = blockIdx.x * 32, by = blockIdx.y * 32;
  const int tx = threadIdx.x & 31, ty = threadIdx.x >> 5;  // 32 x 8
#pragma unroll
  for (int i = 0; i < 4; ++i)
    t[ty + i * 8][tx] = in[(by + ty + i * 8) * 1024 + bx + tx];
  __syncthreads();
#pragma unroll
  for (int i = 0; i < 4; ++i)
    out[(bx + ty + i * 8) * 1024 + by + tx] = f2bf(t[tx][ty + i * 8]);
}

// ------------- b'[h] = bo[h] + sum_k Wo[h,k] * bv[k] -------------
__global__ __launch_bounds__(256) void bias_fuse(const float* __restrict__ Wo,
                                                 const float* __restrict__ bv,
                                                 const float* __restrict__ bo,
                                                 float* __restrict__ bp) {
  const int row = blockIdx.x * 4 + (threadIdx.x >> 6);
  const int lane = threadIdx.x & 63;
  float s = 0.f;
  for (int k = lane; k < 1024; k += 64) s += Wo[row * 1024 + k] * bv[k];
#pragma unroll
  for (int off = 32; off >= 1; off >>= 1) s += __shfl_xor(s, off, 64);
  if (lane == 0) bp[row] = s + bo[row];
}

// ================== 128 x BN TLP-first NT GEMM (BK=32) =====================
// C[m,n] = alpha * sum_k A[m,k]*B[n,k] (+bias). 256 thr = 4 waves (2x2),
// per-wave 64 x BN/2 output. Double-buffered 32KB(BN=128)/24KB(BN=64) LDS ->
// 3 resident blocks/CU; stalls hidden by cross-block TLP (m97/m114 regime).
// BIAS_MODE: 0 none, 1 bias[col], 3 col<1024?bias:bias2.
// EPI: 0 plain, 1 exp(v)+rowsum->Srow atomics, 2 scale by 1/Srow.
template <int BN, int OUT_F32, int BIAS_MODE, int EPI>
__global__ __launch_bounds__(256, 3) void gemm_tlp(
    const unsigned short* __restrict__ A, const unsigned short* __restrict__ B,
    void* __restrict__ Cv, const float* __restrict__ bias,
    const float* __restrict__ bias2, float* __restrict__ Srow, int K, int lda,
    int ldb, int ldc, long long bsA, long long bsB, long long bsC,
    float alpha) {
  static_assert(BN == 128 || BN == 64, "BN");
  constexpr int NF = BN / 32;      // B frags per wave (4 or 2)
  constexpr int CB = BN / 64;      // B staging chunks (2 or 1)

  __shared__ unsigned short lA[2][128 * 32];
  __shared__ unsigned short lB[2][BN * 32];

  const int tid = threadIdx.x;
  const int lane = tid & 63, wid = tid >> 6;
  const int fr = lane & 15, fq = lane >> 4;
  const int wm = wid >> 1, wn = wid & 1;

  // XCD-aware chunked swizzle on flattened (y,x); all grids have nwg%8==0.
  const int nx = gridDim.x;
  const int nwg = nx * gridDim.y;
  int f = blockIdx.y * nx + blockIdx.x;
  f = (f & 7) * (nwg >> 3) + (f >> 3);
  const int bx = f % nx, by = f / nx;
  const int bz = blockIdx.z;

  const unsigned short* Ag = A + bz * bsA + (long long)by * 128 * lda;
  const unsigned short* Bg = B + bz * bsB + (long long)bx * BN * ldb;
  const int NT = K >> 5;

  // Linear staging: wave-uniform LDS base, lane offsets 16B; global source
  // row = c*64 + tid>>2, col = (tid&3)*8 -- fully coalesced 1KB/wave.
  const int srow = tid >> 2, scol = (tid & 3) * 8;
  const int lbase = wid * 512;  // ushorts, wave-uniform

  auto stageA = [&](int t) {
    unsigned short* d0 = &lA[t & 1][lbase];
    GLOAD16(Ag + (long long)srow * lda + t * 32 + scol, d0);
    GLOAD16(Ag + (long long)(64 + srow) * lda + t * 32 + scol, d0 + 2048);
  };
  auto stageB = [&](int t) {
    unsigned short* d0 = &lB[t & 1][lbase];
    GLOAD16(Bg + (long long)srow * ldb + t * 32 + scol, d0);
    if (CB == 2)
      GLOAD16(Bg + (long long)(64 + srow) * ldb + t * 32 + scol, d0 + 2048);
  };

  f32x4 acc[4][NF] = {};

  stageA(0);
  stageB(0);
  __syncthreads();

  for (int t = 0; t < NT; ++t) {
    if (t + 1 < NT) {  // issue next tile early; lands during MFMA below
      stageA(t + 1);
      stageB(t + 1);
    }
    const unsigned short* pa = lA[t & 1];
    const unsigned short* pb = lB[t & 1];
    short8 av[4], bw[NF];
#pragma unroll
    for (int i = 0; i < 4; ++i)
      av[i] = *(const short8*)(pa + (wm * 64 + i * 16 + fr) * 32 + fq * 8);
#pragma unroll
    for (int n = 0; n < NF; ++n)
      bw[n] = *(const short8*)(pb + (wn * (BN / 2) + n * 16 + fr) * 32 + fq * 8);
#pragma unroll
    for (int i = 0; i < 4; ++i)
#pragma unroll
      for (int n = 0; n < NF; ++n)
        acc[i][n] = __builtin_amdgcn_mfma_f32_16x16x32_bf16(av[i], bw[n],
                                                            acc[i][n], 0, 0, 0);
    __syncthreads();  // drains vm+lgkm; publishes tile t+1
  }

  // Epilogue. C/D frag layout: col = 16*frag + fr, row = fq*4 + j.
  const long long cb0 = (long long)bz * bsC;
  float* sredf = (float*)lA;  // [128][2] row-sum scratch (EPI==1)
#pragma unroll
  for (int i = 0; i < 4; ++i)
#pragma unroll
    for (int j = 0; j < 4; ++j) {
      const int row = wm * 64 + i * 16 + fq * 4 + j;
      float inv = 1.0f;
      if (EPI == 2) inv = 1.0f / Srow[(long long)bz * SEQ + by * 128 + row];
      float rps = 0.0f;
#pragma unroll
      for (int n = 0; n < NF; ++n) {
        const int col = bx * BN + wn * (BN / 2) + n * 16 + fr;
        float v = acc[i][n][j] * alpha;
        if (EPI == 1) { v = __expf(v); rps += v; }
        if (EPI == 2) v *= inv;
        if (BIAS_MODE == 1) v += bias[col];
        if (BIAS_MODE == 3) v += (col < 1024) ? bias[col] : bias2[col - 1024];
        const long long idx = cb0 + (long long)(by * 128 + row) * ldc + col;
        if (OUT_F32)
          ((float*)Cv)[idx] = v;
        else
          ((unsigned short*)Cv)[idx] = f2bf(v);
      }
      if (EPI == 1) {
        rps += __shfl_xor(rps, 1, 64);
        rps += __shfl_xor(rps, 2, 64);
        rps += __shfl_xor(rps, 4, 64);
        rps += __shfl_xor(rps, 8, 64);
        if (fr == 0) sredf[row * 2 + wn] = rps;
      }
    }
  if (EPI == 1) {
    __syncthreads();
    if (tid < 128) {
      const float s2 = sredf[tid * 2] + sredf[tid * 2 + 1];
      atomicAdd(Srow + (long long)bz * SEQ + by * 128 + tid, s2);
    }
  }
}

extern "C" void kernel_launch(void* const* d_in, const int* in_sizes, int n_in,
                              void* d_out, int out_size, void* d_ws,
                              size_t ws_size, hipStream_t stream) {
  (void)in_sizes; (void)n_in; (void)out_size; (void)ws_size;
  const float* x = (const float*)d_in[0];
  const float* Wq = (const float*)d_in[1];
  const float* bq = (const float*)d_in[2];
  const float* Wk = (const float*)d_in[3];
  const float* bk = (const float*)d_in[4];
  const float* Wv = (const float*)d_in[5];
  const float* bv = (const float*)d_in[6];
  const float* Wo = (const float*)d_in[7];
  const float* bo = (const float*)d_in[8];
  float* out = (float*)d_out;

  char* ws = (char*)d_ws;
  unsigned short* xbf  = (unsigned short*)(ws + 0);         // 16 MiB
  unsigned short* wqk  = (unsigned short*)(ws + 16777216);  // 4 MiB [2048][1024]
  unsigned short* wobf = (unsigned short*)(ws + 20971520);  // 2 MiB
  unsigned short* wvT  = (unsigned short*)(ws + 23068672);  // 2 MiB (Wv^T)
  unsigned short* wov  = (unsigned short*)(ws + 25165824);  // 2 MiB (Wo.Wv)
  float*          bpr  = (float*)        (ws + 27262976);   // 4 KiB (Wo.bv+bo)
  float*          Srow = (float*)        (ws + 28311552);   // 32 KiB rowsums
  unsigned short* VWoT = (unsigned short*)(ws + 33554432);  // 16 MiB [1024][8192]
  unsigned short* QKb  = (unsigned short*)(ws + 50331648);  // 32 MiB [8192][2048]
  unsigned short* P    = (unsigned short*)(ws + 83886080);  // 32 MiB [4][2048][2048]

  // casts & small precomputes
  cast_f32_to_bf16<<<4096, 256, 0, stream>>>(x, xbf, BS * HID);
  cast_f32_to_bf16<<<512, 256, 0, stream>>>(Wq, wqk, HID * HID);
  cast_f32_to_bf16<<<512, 256, 0, stream>>>(Wk, wqk + HID * HID, HID * HID);
  cast_f32_to_bf16<<<512, 256, 0, stream>>>(Wo, wobf, HID * HID);
  transpose_cast<<<dim3(32, 32), 256, 0, stream>>>(Wv, wvT);
  bias_fuse<<<256, 256, 0, stream>>>(Wo, bv, bo, bpr);
  hipMemsetAsync(Srow, 0, NB * SEQ * sizeof(float), stream);

  // WoWv[h,k] = sum_j Wo[h,j] Wv[j,k] = NT(Wo, Wv^T) : [1024,1024]
  gemm_tlp<128, 0, 0, 0><<<dim3(8, 8, 1), 256, 0, stream>>>(
      wobf, wvT, wov, nullptr, nullptr, nullptr, HID, HID, HID, HID, 0, 0, 0,
      1.0f);
  // VWoT[h,s] = sum_k WoWv[h,k] x[s,k] = NT(WoWv, x) : [1024,8192]
  gemm_tlp<64, 0, 0, 0><<<dim3(128, 8, 1), 256, 0, stream>>>(
      wov, xbf, VWoT, nullptr, nullptr, nullptr, HID, HID, HID, BS, 0, 0, 0,
      1.0f);
  // [Q|K] = x @ [Wq;Wk]^T + [bq;bk] : [8192,2048]
  gemm_tlp<128, 0, 3, 0><<<dim3(16, 64, 1), 256, 0, stream>>>(
      xbf, wqk, QKb, bq, bk, nullptr, HID, HID, HID, 2048, 0, 0, 0, 1.0f);
  // P = exp(Q @ K^T / 32) per batch + rowsums : [4][2048][2048]
  gemm_tlp<128, 0, 0, 1><<<dim3(16, 16, NB), 256, 0, stream>>>(
      QKb, QKb + 1024, P, nullptr, nullptr, Srow, HID, 2048, 2048, SEQ,
      (long long)SEQ * 2048, (long long)SEQ * 2048, (long long)SEQ * SEQ,
      0.03125f);
  // out = (P @ VWoT^T) / Srow + b' : [8192,1024] fp32 (k-window via bsB)
  gemm_tlp<64, 1, 1, 2><<<dim3(16, 16, NB), 256, 0, stream>>>(
      P, VWoT, out, bpr, nullptr, Srow, SEQ, SEQ, BS, HID,
      (long long)SEQ * SEQ, (long long)SEQ, (long long)SEQ * HID, 1.0f);
}

// Round 6
// 227.290 us; speedup vs baseline: 1.1253x; 1.0318x over previous
//
#include <hip/hip_runtime.h>

#define HID 1024
#define SEQ 2048
#define NB 4
#define BS 8192  // NB*SEQ

typedef __attribute__((ext_vector_type(8))) short short8;
typedef __attribute__((ext_vector_type(8))) unsigned short ushort8;
typedef __attribute__((ext_vector_type(4))) float f32x4;

__device__ __forceinline__ float bf2f(unsigned short u) {
  unsigned int x = ((unsigned int)u) << 16;
  return __builtin_bit_cast(float, x);
}
__device__ __forceinline__ unsigned short f2bf(float f) {
  unsigned int x = __builtin_bit_cast(unsigned int, f);
  x = x + 0x7fffu + ((x >> 16) & 1u);
  return (unsigned short)(x >> 16);
}

#define GLOAD16(g, l)                                                          \
  __builtin_amdgcn_global_load_lds(                                            \
      (const __attribute__((address_space(1))) unsigned int*)(g),              \
      (__attribute__((address_space(3))) unsigned int*)(l), 16, 0, 0)

// ---------------- fp32 -> bf16 cast, 8 elems/thread ----------------
__global__ void cast_f32_to_bf16(const float* __restrict__ in,
                                 unsigned short* __restrict__ out, int n) {
  int i = (blockIdx.x * 256 + threadIdx.x) * 8;
  if (i >= n) return;
  f32x4 a = *(const f32x4*)(in + i);
  f32x4 b = *(const f32x4*)(in + i + 4);
  ushort8 o;
  o[0] = f2bf(a[0]); o[1] = f2bf(a[1]); o[2] = f2bf(a[2]); o[3] = f2bf(a[3]);
  o[4] = f2bf(b[0]); o[5] = f2bf(b[1]); o[6] = f2bf(b[2]); o[7] = f2bf(b[3]);
  *(ushort8*)(out + i) = o;
}

// ------------- 1024x1024 fp32 -> bf16 transposed cast -------------
__global__ __launch_bounds__(256) void transpose_cast(
    const float* __restrict__ in, unsigned short* __restrict__ out) {
  __shared__ float t[32][33];
  const int bx = blockIdx.x * 32, by = blockIdx.y * 32;
  const int tx = threadIdx.x & 31, ty = threadIdx.x >> 5;  // 32 x 8
#pragma unroll
  for (int i = 0; i < 4; ++i)
    t[ty + i * 8][tx] = in[(by + ty + i * 8) * 1024 + bx + tx];
  __syncthreads();
#pragma unroll
  for (int i = 0; i < 4; ++i)
    out[(bx + ty + i * 8) * 1024 + by + tx] = f2bf(t[tx][ty + i * 8]);
}

// ------------- b'[h] = bo[h] + sum_k Wo[h,k] * bv[k] -------------
__global__ __launch_bounds__(256) void bias_fuse(const float* __restrict__ Wo,
                                                 const float* __restrict__ bv,
                                                 const float* __restrict__ bo,
                                                 float* __restrict__ bp) {
  const int row = blockIdx.x * 4 + (threadIdx.x >> 6);
  const int lane = threadIdx.x & 63;
  float s = 0.f;
  for (int k = lane; k < 1024; k += 64) s += Wo[row * 1024 + k] * bv[k];
#pragma unroll
  for (int off = 32; off >= 1; off >>= 1) s += __shfl_xor(s, off, 64);
  if (lane == 0) bp[row] = s + bo[row];
}

// ================== 128 x BN TLP-first NT GEMM (BK=32) =====================
// C[m,n] = alpha * sum_k A[m,k]*B[n,k] (+bias). 256 thr = 4 waves (2x2),
// per-wave 64 x BN/2 output. Double-buffered LDS, 3 resident blocks/CU.
// LDS tiles are XOR-swizzled (phys = L ^ (((L>>8)&3)<<4), 64B rows): the
// swizzle is applied to the GLOBAL source column while the gload_lds dest
// stays linear, and to the fq-slot of every ds_read (rule 21, involution).
// This makes each 16-consecutive-lane group of a b128 read hit every bank
// residue exactly 2x -> conflict-free (m136: 2-way is free).
// BIAS_MODE: 0 none, 1 bias[col], 3 col<1024?bias:bias2.
// EPI: 0 plain, 1 exp(v)+rowsum->Srow atomics, 2 scale by 1/Srow.
template <int BN, int OUT_F32, int BIAS_MODE, int EPI>
__global__ __launch_bounds__(256, 3) void gemm_tlp(
    const unsigned short* __restrict__ A, const unsigned short* __restrict__ B,
    void* __restrict__ Cv, const float* __restrict__ bias,
    const float* __restrict__ bias2, float* __restrict__ Srow, int K, int lda,
    int ldb, int ldc, long long bsA, long long bsB, long long bsC,
    float alpha) {
  static_assert(BN == 128 || BN == 64, "BN");
  constexpr int NF = BN / 32;      // B frags per wave (4 or 2)
  constexpr int CB = BN / 64;      // B staging chunks (2 or 1)

  __shared__ unsigned short lA[2][128 * 32];
  __shared__ unsigned short lB[2][BN * 32];

  const int tid = threadIdx.x;
  const int lane = tid & 63, wid = tid >> 6;
  const int fr = lane & 15, fq = lane >> 4;
  const int wm = wid >> 1, wn = wid & 1;

  // XCD-aware chunked swizzle on flattened (y,x); all grids have nwg%8==0.
  const int nx = gridDim.x;
  const int nwg = nx * gridDim.y;
  int f = blockIdx.y * nx + blockIdx.x;
  f = (f & 7) * (nwg >> 3) + (f >> 3);
  const int bx = f % nx, by = f / nx;
  const int bz = blockIdx.z;

  const unsigned short* Ag = A + bz * bsA + (long long)by * 128 * lda;
  const unsigned short* Bg = B + bz * bsB + (long long)bx * BN * ldb;
  const int NT = K >> 5;

  // Staging: LDS dest linear (wave-uniform base + lane*16B); global source
  // column pre-swizzled so logical layout lands XOR-swizzled in LDS.
  const int srow = tid >> 2;                                  // logical row
  const int scol = 8 * ((tid & 3) ^ ((tid >> 4) & 3));        // swizzled col
  const int lbase = wid * 512;  // ushorts, wave-uniform

  auto stageA = [&](int t) {
    unsigned short* d0 = &lA[t & 1][lbase];
    GLOAD16(Ag + (long long)srow * lda + t * 32 + scol, d0);
    GLOAD16(Ag + (long long)(64 + srow) * lda + t * 32 + scol, d0 + 2048);
  };
  auto stageB = [&](int t) {
    unsigned short* d0 = &lB[t & 1][lbase];
    GLOAD16(Bg + (long long)srow * ldb + t * 32 + scol, d0);
    if (CB == 2)
      GLOAD16(Bg + (long long)(64 + srow) * ldb + t * 32 + scol, d0 + 2048);
  };

  // Fragment read offsets: XOR the fq-slot with row bits 2-3 (= fr bits 2-3).
  const int xm = ((fr >> 2) & 3) << 3;  // ushort-unit XOR mask (bits 3-4)

  f32x4 acc[4][NF] = {};

  stageA(0);
  stageB(0);
  __syncthreads();

  for (int t = 0; t < NT; ++t) {
    if (t + 1 < NT) {  // issue next tile early; lands during MFMA below
      stageA(t + 1);
      stageB(t + 1);
    }
    const unsigned short* pa = lA[t & 1];
    const unsigned short* pb = lB[t & 1];
    short8 av[4], bw[NF];
#pragma unroll
    for (int i = 0; i < 4; ++i)
      av[i] = *(const short8*)(pa +
                               (((wm * 64 + i * 16 + fr) * 32 + fq * 8) ^ xm));
#pragma unroll
    for (int n = 0; n < NF; ++n)
      bw[n] = *(const short8*)(pb + (((wn * (BN / 2) + n * 16 + fr) * 32 +
                                      fq * 8) ^ xm));
#pragma unroll
    for (int i = 0; i < 4; ++i)
#pragma unroll
      for (int n = 0; n < NF; ++n)
        acc[i][n] = __builtin_amdgcn_mfma_f32_16x16x32_bf16(av[i], bw[n],
                                                            acc[i][n], 0, 0, 0);
    __syncthreads();  // drains vm+lgkm; publishes tile t+1
  }

  // Epilogue. C/D frag layout: col = 16*frag + fr, row = fq*4 + j.
  const long long cb0 = (long long)bz * bsC;
  float* sredf = (float*)lA;  // [128][2] row-sum scratch (EPI==1)
#pragma unroll
  for (int i = 0; i < 4; ++i)
#pragma unroll
    for (int j = 0; j < 4; ++j) {
      const int row = wm * 64 + i * 16 + fq * 4 + j;
      float inv = 1.0f;
      if (EPI == 2) inv = 1.0f / Srow[(long long)bz * SEQ + by * 128 + row];
      float rps = 0.0f;
#pragma unroll
      for (int n = 0; n < NF; ++n) {
        const int col = bx * BN + wn * (BN / 2) + n * 16 + fr;
        float v = acc[i][n][j] * alpha;
        if (EPI == 1) { v = __expf(v); rps += v; }
        if (EPI == 2) v *= inv;
        if (BIAS_MODE == 1) v += bias[col];
        if (BIAS_MODE == 3) v += (col < 1024) ? bias[col] : bias2[col - 1024];
        const long long idx = cb0 + (long long)(by * 128 + row) * ldc + col;
        if (OUT_F32)
          ((float*)Cv)[idx] = v;
        else
          ((unsigned short*)Cv)[idx] = f2bf(v);
      }
      if (EPI == 1) {
        rps += __shfl_xor(rps, 1, 64);
        rps += __shfl_xor(rps, 2, 64);
        rps += __shfl_xor(rps, 4, 64);
        rps += __shfl_xor(rps, 8, 64);
        if (fr == 0) sredf[row * 2 + wn] = rps;
      }
    }
  if (EPI == 1) {
    __syncthreads();
    if (tid < 128) {
      const float s2 = sredf[tid * 2] + sredf[tid * 2 + 1];
      atomicAdd(Srow + (long long)bz * SEQ + by * 128 + tid, s2);
    }
  }
}

extern "C" void kernel_launch(void* const* d_in, const int* in_sizes, int n_in,
                              void* d_out, int out_size, void* d_ws,
                              size_t ws_size, hipStream_t stream) {
  (void)in_sizes; (void)n_in; (void)out_size; (void)ws_size;
  const float* x = (const float*)d_in[0];
  const float* Wq = (const float*)d_in[1];
  const float* bq = (const float*)d_in[2];
  const float* Wk = (const float*)d_in[3];
  const float* bk = (const float*)d_in[4];
  const float* Wv = (const float*)d_in[5];
  const float* bv = (const float*)d_in[6];
  const float* Wo = (const float*)d_in[7];
  const float* bo = (const float*)d_in[8];
  float* out = (float*)d_out;

  char* ws = (char*)d_ws;
  unsigned short* xbf  = (unsigned short*)(ws + 0);         // 16 MiB
  unsigned short* wqk  = (unsigned short*)(ws + 16777216);  // 4 MiB [2048][1024]
  unsigned short* wobf = (unsigned short*)(ws + 20971520);  // 2 MiB
  unsigned short* wvT  = (unsigned short*)(ws + 23068672);  // 2 MiB (Wv^T)
  unsigned short* wov  = (unsigned short*)(ws + 25165824);  // 2 MiB (Wo.Wv)
  float*          bpr  = (float*)        (ws + 27262976);   // 4 KiB (Wo.bv+bo)
  float*          Srow = (float*)        (ws + 28311552);   // 32 KiB rowsums
  unsigned short* VWoT = (unsigned short*)(ws + 33554432);  // 16 MiB [1024][8192]
  unsigned short* QKb  = (unsigned short*)(ws + 50331648);  // 32 MiB [8192][2048]
  unsigned short* P    = (unsigned short*)(ws + 83886080);  // 32 MiB [4][2048][2048]

  // casts & small precomputes
  cast_f32_to_bf16<<<4096, 256, 0, stream>>>(x, xbf, BS * HID);
  cast_f32_to_bf16<<<512, 256, 0, stream>>>(Wq, wqk, HID * HID);
  cast_f32_to_bf16<<<512, 256, 0, stream>>>(Wk, wqk + HID * HID, HID * HID);
  cast_f32_to_bf16<<<512, 256, 0, stream>>>(Wo, wobf, HID * HID);
  transpose_cast<<<dim3(32, 32), 256, 0, stream>>>(Wv, wvT);
  bias_fuse<<<256, 256, 0, stream>>>(Wo, bv, bo, bpr);
  hipMemsetAsync(Srow, 0, NB * SEQ * sizeof(float), stream);

  // WoWv[h,k] = sum_j Wo[h,j] Wv[j,k] = NT(Wo, Wv^T) : [1024,1024]
  gemm_tlp<128, 0, 0, 0><<<dim3(8, 8, 1), 256, 0, stream>>>(
      wobf, wvT, wov, nullptr, nullptr, nullptr, HID, HID, HID, HID, 0, 0, 0,
      1.0f);
  // VWoT[h,s] = sum_k WoWv[h,k] x[s,k] = NT(WoWv, x) : [1024,8192]
  gemm_tlp<128, 0, 0, 0><<<dim3(64, 8, 1), 256, 0, stream>>>(
      wov, xbf, VWoT, nullptr, nullptr, nullptr, HID, HID, HID, BS, 0, 0, 0,
      1.0f);
  // [Q|K] = x @ [Wq;Wk]^T + [bq;bk] : [8192,2048]
  gemm_tlp<128, 0, 3, 0><<<dim3(16, 64, 1), 256, 0, stream>>>(
      xbf, wqk, QKb, bq, bk, nullptr, HID, HID, HID, 2048, 0, 0, 0, 1.0f);
  // P = exp(Q @ K^T / 32) per batch + rowsums : [4][2048][2048]
  gemm_tlp<128, 0, 0, 1><<<dim3(16, 16, NB), 256, 0, stream>>>(
      QKb, QKb + 1024, P, nullptr, nullptr, Srow, HID, 2048, 2048, SEQ,
      (long long)SEQ * 2048, (long long)SEQ * 2048, (long long)SEQ * SEQ,
      0.03125f);
  // out = (P @ VWoT^T) / Srow + b' : [8192,1024] fp32 (k-window via bsB)
  gemm_tlp<128, 1, 1, 2><<<dim3(8, 16, NB), 256, 0, stream>>>(
      P, VWoT, out, bpr, nullptr, Srow, SEQ, SEQ, BS, HID,
      (long long)SEQ * SEQ, (long long)SEQ, (long long)SEQ * HID, 1.0f);
}